// Round 5
// baseline (502.247 us; speedup 1.0000x reference)
//
#include <hip/hip_runtime.h>
#include <hip/hip_bf16.h>

constexpr int N_NODES = 500000;
constexpr int N_Q     = 500000;
constexpr int H       = 8;
constexpr int FEAT    = 64;                      // H * MH
constexpr int NT      = (N_NODES + 63) / 64;     // 7813 node tiles (sort radix)

// ws layout: int2 perm[N_Q] | int cnt[NT] | int ofs_unused[NT] | int cursor[NT]

// ---------------------------------------------------------------------------
// Sort chain: counting sort of queries by node tile (j >> 6).
// ---------------------------------------------------------------------------
__global__ __launch_bounds__(256) void k_zero(int* __restrict__ cnt)
{
    const int i = blockIdx.x * 256 + threadIdx.x;
    if (i < NT) cnt[i] = 0;
}

__global__ __launch_bounds__(256) void k_hist(const int* __restrict__ k_idx,
                                              int* __restrict__ cnt)
{
    const int q = blockIdx.x * 256 + threadIdx.x;
    if (q < N_Q) atomicAdd(&cnt[k_idx[q] >> 6], 1);
}

// single-block exclusive scan over NT elements -> cursor
__global__ __launch_bounds__(1024) void k_scan(const int* __restrict__ cnt,
                                               int* __restrict__ cursor)
{
    __shared__ int lds[1024];
    __shared__ int running;
    const int t = threadIdx.x;
    if (t == 0) running = 0;
    __syncthreads();
    for (int base = 0; base < NT; base += 1024) {
        const int i = base + t;
        const int v = (i < NT) ? cnt[i] : 0;
        lds[t] = v;
        __syncthreads();
        for (int off = 1; off < 1024; off <<= 1) {
            const int x = (t >= off) ? lds[t - off] : 0;
            __syncthreads();
            lds[t] += x;
            __syncthreads();
        }
        const int excl = lds[t] - v + running;
        if (i < NT) cursor[i] = excl;
        const int total = lds[1023];
        __syncthreads();
        if (t == 0) running += total;
        __syncthreads();
    }
}

__global__ __launch_bounds__(256) void k_scatter(const int* __restrict__ k_idx,
                                                 int* __restrict__ cursor,
                                                 int2* __restrict__ perm)
{
    const int q = blockIdx.x * 256 + threadIdx.x;
    if (q < N_Q) {
        const int j = k_idx[q];
        const int p = atomicAdd(&cursor[j >> 6], 1);
        perm[p] = make_int2(q, j);
    }
}

// ---------------------------------------------------------------------------
// Main: thread per (sorted-query p, head h). No LDS, no barriers.
//   perm   : 8B broadcast-ish load (8 lanes share one entry)
//   q_phi  : 2x float4, full 256B-granule use per query
//   pk     : 16 dword gathers; j clustered within wave -> each 64B line
//            serves ~16 consecutive sorted queries (L1/L2 temporal reuse)
//   deg    : j-sorted -> near-sequential 32B granules
//   out    : scattered 32B granules, nontemporal
// All loads independent -> deep MLP; occupancy limited only by VGPRs.
// ---------------------------------------------------------------------------
__global__ __launch_bounds__(256) void k_gather_sorted(
    const float* __restrict__ q_phi,
    const float* __restrict__ pk_pos,
    const float* __restrict__ pk_neg,
    const float* __restrict__ deg_pos,
    const float* __restrict__ deg_neg,
    const int2*  __restrict__ perm,
    float*       __restrict__ out)
{
    const int i = blockIdx.x * 256 + threadIdx.x;   // flat (p,h); grid exact
    const int p = i >> 3;
    const int h = i & 7;

    const int2 pj = perm[p];
    const int q = pj.x;
    const int j = pj.y;

    const float4* qp = (const float4*)(q_phi + (size_t)q * FEAT + h * 8);
    const float4 a0 = qp[0], a1 = qp[1];

    const float* bp = pk_pos + (size_t)(h * 8) * N_NODES + j;
    const float* bn = pk_neg + (size_t)(h * 8) * N_NODES + j;

    float vp[8], vn[8];
#pragma unroll
    for (int f = 0; f < 8; ++f) vp[f] = bp[(size_t)f * N_NODES];
#pragma unroll
    for (int f = 0; f < 8; ++f) vn[f] = bn[(size_t)f * N_NODES];

    const float sp = a0.x * vp[0] + a0.y * vp[1] + a0.z * vp[2] + a0.w * vp[3]
                   + a1.x * vp[4] + a1.y * vp[5] + a1.z * vp[6] + a1.w * vp[7];
    const float sn = a0.x * vn[0] + a0.y * vn[1] + a0.z * vn[2] + a0.w * vn[3]
                   + a1.x * vn[4] + a1.y * vn[5] + a1.z * vn[6] + a1.w * vn[7];

    const float dp = fmaxf(deg_pos[(size_t)j * H + h], 1.0f);
    const float dn = fmaxf(deg_neg[(size_t)j * H + h], 1.0f);

    const size_t o = (size_t)q * H + h;
    __builtin_nontemporal_store(sp / dp, &out[o]);
    __builtin_nontemporal_store(sn / dn, &out[(size_t)N_Q * H + o]);
}

// ---------------------------------------------------------------------------
// Fallback (R0 path) if workspace is too small.
// ---------------------------------------------------------------------------
__global__ __launch_bounds__(256, 4) void iskde_gather_kernel(
    const float* __restrict__ q_phi,
    const float* __restrict__ pk_pos,
    const float* __restrict__ pk_neg,
    const float* __restrict__ deg_pos,
    const float* __restrict__ deg_neg,
    const int*   __restrict__ k_idx,
    float*       __restrict__ out)
{
    const int wave_in_blk = threadIdx.x >> 6;
    const int lane        = threadIdx.x & 63;
    const int q           = blockIdx.x * 4 + wave_in_blk;
    if (q >= N_Q) return;

    const int j = k_idx[q];
    const float qv = q_phi[(size_t)q * FEAT + lane];
    const size_t col = (size_t)lane * (size_t)N_NODES + (size_t)j;
    const float pv = pk_pos[col];
    const float nv = pk_neg[col];

    float sp = qv * pv;
    float sn = qv * nv;
    sp += __shfl_xor(sp, 1, 64);
    sn += __shfl_xor(sn, 1, 64);
    sp += __shfl_xor(sp, 2, 64);
    sn += __shfl_xor(sn, 2, 64);
    sp += __shfl_xor(sp, 4, 64);
    sn += __shfl_xor(sn, 4, 64);

    if ((lane & 7) == 0) {
        const int h = lane >> 3;
        const float dp = fmaxf(deg_pos[(size_t)j * H + h], 1.0f);
        const float dn = fmaxf(deg_neg[(size_t)j * H + h], 1.0f);
        const size_t o = (size_t)q * H + h;
        out[o]                   = sp / dp;
        out[(size_t)N_Q * H + o] = sn / dn;
    }
}

extern "C" void kernel_launch(void* const* d_in, const int* in_sizes, int n_in,
                              void* d_out, int out_size, void* d_ws, size_t ws_size,
                              hipStream_t stream) {
    const float* q_phi   = (const float*)d_in[0];
    const float* pk_pos  = (const float*)d_in[1];
    const float* pk_neg  = (const float*)d_in[2];
    const float* deg_pos = (const float*)d_in[3];
    const float* deg_neg = (const float*)d_in[4];
    const int*   k_idx   = (const int*)d_in[5];
    float*       out     = (float*)d_out;

    const size_t need = (size_t)N_Q * sizeof(int2) + 2 * (size_t)NT * sizeof(int);

    if (ws_size >= need) {
        int2* perm   = (int2*)d_ws;
        int*  cnt    = (int*)(perm + N_Q);
        int*  cursor = cnt + NT;

        const int gq = (N_Q + 255) / 256;        // 1954
        const int gt = (NT + 255) / 256;         // 31

        k_zero<<<gt, 256, 0, stream>>>(cnt);
        k_hist<<<gq, 256, 0, stream>>>(k_idx, cnt);
        k_scan<<<1, 1024, 0, stream>>>(cnt, cursor);
        k_scatter<<<gq, 256, 0, stream>>>(k_idx, cursor, perm);

        const int gm = (N_Q * H) / 256;          // 15625, exact
        k_gather_sorted<<<gm, 256, 0, stream>>>(
            q_phi, pk_pos, pk_neg, deg_pos, deg_neg, perm, out);
    } else {
        const int blocks = (N_Q + 3) / 4;
        iskde_gather_kernel<<<blocks, 256, 0, stream>>>(
            q_phi, pk_pos, pk_neg, deg_pos, deg_neg, k_idx, out);
    }
}